// Round 7
// baseline (814.267 us; speedup 1.0000x reference)
//
#include <hip/hip_runtime.h>
#include <math.h>
#include <float.h>

#define B_   16
#define N_   4096
#define CIN  3
#define COUT 64
#define KNN  20
#define EPS_ 1e-5
#define SEED 64     // morton-adjacent same-quarter seed window (exact-d bound)
#define SVC  24     // survivor slots per lane (LDS [SVC][512] u16)

// ---------------------------------------------------------------------------
// Workspace layout (5.5MB proven-safe footprint):
//   [0,   216): double stats[27]
//   [256, 768): float scale[64], shift[64]
//   [1024, +B*N*KNN*4): int idx[B*N*KNN]
//   [5243904, +B*N*4): int perm[B*N]
//
// knn LDS (80KB dynamic, 2 blocks/CU), quarter-major SoA:
//   [0,  16K): xs_q[4][1024]   [16K,32K): ys_q   [32K,48K): zs_q
//   [48K,56K): j16_q[4][1024] u16
//   [56K,80K): svb[SVC][512] u16 (bank = tid/2 -> 2-way = free)
//   merge-scratch double view overlays [0, 40K) after scans complete.
//
// r6 post-mortem: prefill-derived ub (20 samples over an 80-pos window) was
// LOOSE -> survivors >> SVC -> frequent overflow re-scans (wave-union f64
// inserts) + scratch pressure: issue-cy/wave ROSE to 220k (vs r1 162k) and
// spill evictions added 4.8MB HBM writes. This round the bound is the EXACT
// quarter 20th-smallest d, built incrementally in f32 (w[20], 20 VGPRs):
// seed with 64 morton-adjacent quarter candidates (spatially tight), then
// linear-scan the rest maintaining w + recording d<=w[19] survivors.
// bk (f64) is born only after the scans (r5's liveness lesson).
// ---------------------------------------------------------------------------

__device__ __forceinline__ unsigned expand10(unsigned v) {
    v = (v | (v << 16)) & 0x030000FFu;
    v = (v | (v << 8))  & 0x0300F00Fu;
    v = (v | (v << 4))  & 0x030C30C3u;
    v = (v | (v << 2))  & 0x09249249u;
    return v;
}
__device__ __forceinline__ unsigned quant10(float v) {
    int q = (int)((v + 4.0f) * 128.0f);
    return (unsigned)min(1023, max(0, q));
}

// ===========================================================================
// Kernel 0: per-batch Morton COUNTING sort (unchanged, verified)
// ===========================================================================
__global__ __launch_bounds__(1024) void morton_bucket_kernel(
    const float* __restrict__ x, int* __restrict__ perm)
{
    __shared__ int hist[1024];
    __shared__ int scanbuf[1024];
    __shared__ int offs[1024];
    const int b = blockIdx.x, tid = threadIdx.x;
    const float* xb = x + (size_t)b * N_ * CIN;

    hist[tid] = 0;
    __syncthreads();

    int keys[4];
#pragma unroll
    for (int i = 0; i < 4; ++i) {
        int p = tid + i * 1024;
        float v0 = xb[p * 3 + 0], v1 = xb[p * 3 + 1], v2 = xb[p * 3 + 2];
        unsigned m = (expand10(quant10(v0)) << 2) |
                     (expand10(quant10(v1)) << 1) |
                      expand10(quant10(v2));
        keys[i] = (int)(m >> 20);          // top 10 bits
        atomicAdd(&hist[keys[i]], 1);
    }
    __syncthreads();

    int v = hist[tid];
    scanbuf[tid] = v;
    __syncthreads();
    for (int off = 1; off < 1024; off <<= 1) {   // Hillis-Steele inclusive
        int t = (tid >= off) ? scanbuf[tid - off] : 0;
        __syncthreads();
        scanbuf[tid] += t;
        __syncthreads();
    }
    offs[tid] = scanbuf[tid] - v;                // exclusive base
    __syncthreads();

#pragma unroll
    for (int i = 0; i < 4; ++i) {
        int p = tid + i * 1024;
        int pos = atomicAdd(&offs[keys[i]], 1);
        perm[b * N_ + pos] = p;
    }
}

// ===========================================================================
// Kernel 1: exact-match KNN — exact-bound filter-then-select.
// Correctness chain:
//  1. w[20] = f32 sorted 20-smallest exact d over ALL 1024 quarter candidates
//     (seed 64 + scan 960, each exactly once). w19f := w[19] = EXACT quarter
//     d_(20). Every quarter top-20-by-key member has d <= w19f.
//  2. scan records non-seed candidates with d <= w[19]-at-visit (>= w19f)
//     -> superset of non-seed members. Non-strict gate keeps d-ties.
//  3. key phase: bk built by the VERBATIM verified f64 sorted-shift insert
//     from {seeds with d <= w19f} u {recorded survivors}; overflow past SVC
//     (rare) -> filtered re-scan, each candidate inserted exactly once.
//  4. 2-round merge / extraction / BN stats: byte-identical verified code.
// ===========================================================================
__global__ __launch_bounds__(512) void knn_f64_kernel(
    const float* __restrict__ x, const int* __restrict__ perm,
    int* __restrict__ idx_out, double* __restrict__ stats)
{
    extern __shared__ __align__(16) char smem[];
    float* xs_q = (float*)smem;                              // [4][1024]
    float* ys_q = (float*)(smem + 16384);                    // [4][1024]
    float* zs_q = (float*)(smem + 32768);                    // [4][1024]
    unsigned short* j16_q = (unsigned short*)(smem + 49152); // [4][1024]
    unsigned short* svb   = (unsigned short*)(smem + 57344); // [SVC][512]
    double* scr = (double*)smem;                             // merge view

    const int b    = blockIdx.y;
    const int tid  = threadIdx.x;
    const int wave = tid >> 6;
    const int lane = tid & 63;
    const int r    = wave >> 2;     // row-group 0..1
    const int q    = wave & 3;      // interleave class: positions p&3==q
    const float* xb = x + (size_t)b * N_ * CIN;

    for (int p = tid; p < N_; p += 512) {
        int j = perm[b * N_ + p];                // coalesced
        int qq = p & 3, tt = p >> 2;
        xs_q[qq * 1024 + tt] = xb[j * 3 + 0];
        ys_q[qq * 1024 + tt] = xb[j * 3 + 1];
        zs_q[qq * 1024 + tt] = xb[j * 3 + 2];
        j16_q[qq * 1024 + tt] = (unsigned short)j;
    }
    __syncthreads();

    const int rowg = blockIdx.x * 128 + r * 64;  // wave's first row pos
    const int rp   = rowg + lane;
    const int rq = rp & 3, rt = rp >> 2;
    const float xfx = xs_q[rq * 1024 + rt];
    const float xfy = ys_q[rq * 1024 + rt];
    const float xfz = zs_q[rq * 1024 + rt];
    const int jrow  = j16_q[rq * 1024 + rt];
    const float sqi = __fadd_rn(__fadd_rn(__fmul_rn(xfx, xfx),
                                          __fmul_rn(xfy, xfy)),
                                __fmul_rn(xfz, xfz));

    // exact f32 distance: bit-identical to the np/jax reference expansion
    auto mkd3 = [&](float px, float py, float pz) -> float {
        float sqj = __fadd_rn(__fadd_rn(__fmul_rn(px, px),
                                        __fmul_rn(py, py)),
                              __fmul_rn(pz, pz));
        float dot = __fadd_rn(__fadd_rn(__fmul_rn(xfx, px),
                                        __fmul_rn(xfy, py)),
                              __fmul_rn(xfz, pz));
        return __fsub_rn(__fadd_rn(sqi, sqj), __fmul_rn(2.0f, dot));
    };
    const float* xq = xs_q + q * 1024;
    const float* yq = ys_q + q * 1024;
    const float* zq = zs_q + q * 1024;
    const unsigned short* jq = j16_q + q * 1024;

    auto dkey = [&](float d, int j) -> double {   // verified sortable map
        unsigned u = __float_as_uint(d);
        unsigned s = u ^ (0x80000000u | (unsigned)((int)u >> 31));
        return fma((double)s, 4096.0, (double)(unsigned)j);
    };

    const int ta = rowg >> 2;            // wave-uniform anchor

    // ---- phase 1a: seed w (f32 sorted top-20 d) from 64-window ----
    float w[KNN];
#pragma unroll
    for (int k = 0; k < KNN; ++k) w[k] = 1e30f;
    for (int k = 0; k < SEED; ++k) {
        int t = (ta + k) & 1023;
        float d = mkd3(xq[t], yq[t], zq[t]);
        if (d < w[KNN - 1]) {
            float m = d;
#pragma unroll
            for (int kk = 0; kk < KNN; ++kk) {
                float old = w[kk];
                w[kk] = fminf(m, old);
                m     = fmaxf(old, m);
            }
        }
    }

    // ---- phase 1b: linear scan of the rest; maintain w, record survivors --
    unsigned cnt = 0;
    for (int t = 0; t < 1024; t += 4) {
        float4 xv = *(const float4*)(xq + t);     // wave-uniform b128
        float4 yv = *(const float4*)(yq + t);
        float4 zv = *(const float4*)(zq + t);
        float dd[4];
        dd[0] = mkd3(xv.x, yv.x, zv.x);
        dd[1] = mkd3(xv.y, yv.y, zv.y);
        dd[2] = mkd3(xv.z, yv.z, zv.z);
        dd[3] = mkd3(xv.w, yv.w, zv.w);
#pragma unroll
        for (int i = 0; i < 4; ++i) {
            int ti = t + i;
            float d = dd[i];
            bool notseed = ((unsigned)((ti - ta) & 1023) >= (unsigned)SEED);
            float w19 = w[KNN - 1];
            bool rec = notseed && (d <= w19);     // non-strict: keep d-ties
            if (rec && cnt < SVC) svb[cnt * 512 + tid] = (unsigned short)ti;
            cnt += (unsigned)rec;
            if (notseed && (d < w19)) {           // maintain exact top-20 d
                float m = d;
#pragma unroll
                for (int kk = 0; kk < KNN; ++kk) {
                    float old = w[kk];
                    w[kk] = fminf(m, old);
                    m     = fmaxf(old, m);
                }
            }
        }
    }
    const float w19f = w[KNN - 1];   // EXACT quarter d_(20)

    // ---- phase 2: build bk (verified machinery, born after scans) ----
    double bk[KNN];
#pragma unroll
    for (int k = 0; k < KNN; ++k) bk[k] = 1e300;     // sentinels (sorted)

    auto insert = [&](double key) {                  // VERBATIM verified
        if (key < bk[KNN - 1]) {
            double m = key;
#pragma unroll
            for (int k = 0; k < KNN; ++k) {
                double old = bk[k];
                bk[k] = fmin(m, old);
                m     = fmax(old, m);
            }
        }
    };

    // seed keys, gated by the exact bound (seeds beyond it can't be top-20)
    for (int k = 0; k < SEED; ++k) {
        int t = (ta + k) & 1023;
        float d = mkd3(xq[t], yq[t], zq[t]);
        if (d <= w19f) insert(dkey(d, jq[t]));
    }

    if (cnt <= (unsigned)SVC) {
        for (unsigned i = 0; i < cnt; ++i) {
            int t = svb[i * 512 + tid];
            float d = mkd3(xq[t], yq[t], zq[t]);
            insert(dkey(d, jq[t]));
        }
    } else {
        // overflow (rare): filtered re-scan, each candidate exactly once
        for (int t = 0; t < 1024; ++t) {
            bool notseed = ((unsigned)((t - ta) & 1023) >= (unsigned)SEED);
            if (notseed) {
                float d = mkd3(xq[t], yq[t], zq[t]);
                if (d <= w19f) insert(dkey(d, jq[t]));
            }
        }
    }
    __syncthreads();    // scans done; SoA tile dead -> scr valid

    // ---- merge round A: q1 -> slot0, q3 -> slot1 (verbatim verified) ----
    if (q & 1) {
        int base = ((r * 2 + (q >> 1)) * 64 + lane) * KNN;
#pragma unroll
        for (int k = 0; k < KNN; ++k) scr[base + k] = bk[k];
    }
    __syncthreads();
    if (!(q & 1)) {                 // q0 absorbs q1; q2 absorbs q3
        int base = ((r * 2 + (q >> 1)) * 64 + lane) * KNN;
#pragma unroll
        for (int k = 0; k < KNN; ++k) insert(scr[base + k]);
    }
    __syncthreads();
    if (q == 2) {
        int base = ((r * 2 + 1) * 64 + lane) * KNN;
#pragma unroll
        for (int k = 0; k < KNN; ++k) scr[base + k] = bk[k];
    }
    __syncthreads();
    if (q == 0) {
        int base = ((r * 2 + 1) * 64 + lane) * KNN;
#pragma unroll
        for (int k = 0; k < KNN; ++k) insert(scr[base + k]);

        const long long row = (long long)b * N_ + jrow;
        int bi[KNN];
#pragma unroll
        for (int k = 0; k < KNN; ++k) {
            double sp = trunc(bk[k] * (1.0 / 4096.0));
            bi[k] = (int)(bk[k] - sp * 4096.0);
        }
#pragma unroll
        for (int k = 0; k < KNN; ++k) idx_out[row * KNN + k] = bi[k];

        float acc[27];
#pragma unroll
        for (int t = 0; t < 27; ++t) acc[t] = 0.0f;
#pragma unroll
        for (int k = 0; k < KNN; ++k) {
            const float* pj = xb + bi[k] * 3;
            float e[6] = { xfx, xfy, xfz,
                           pj[0] - xfx, pj[1] - xfy, pj[2] - xfz };
            int t = 6;
#pragma unroll
            for (int a = 0; a < 6; ++a) {
                acc[a] += e[a];
#pragma unroll
                for (int bb = a; bb < 6; ++bb) acc[t++] += e[a] * e[bb];
            }
        }
#pragma unroll
        for (int t = 0; t < 27; ++t) {
            float v = acc[t];
            v += __shfl_down(v, 32); v += __shfl_down(v, 16);
            v += __shfl_down(v, 8);  v += __shfl_down(v, 4);
            v += __shfl_down(v, 2);  v += __shfl_down(v, 1);
            acc[t] = v;
        }
        if (lane == 0) {
#pragma unroll
            for (int t = 0; t < 27; ++t) atomicAdd(&stats[t], (double)acc[t]);
        }
    }
}

// ===========================================================================
// Kernel 2: fold stats -> per-channel scale/shift (unchanged, verified)
// ===========================================================================
__global__ void bn_prep_kernel(
    const double* __restrict__ stats,
    const float* __restrict__ w1, const float* __restrict__ b1,
    const float* __restrict__ gamma, const float* __restrict__ beta,
    float* __restrict__ scale_shift)
{
    const int c = threadIdx.x;
    double s[6], S[6][6];
#pragma unroll
    for (int a = 0; a < 6; ++a) s[a] = stats[a];
    int t = 6;
#pragma unroll
    for (int a = 0; a < 6; ++a)
#pragma unroll
        for (int bb = a; bb < 6; ++bb) { S[a][bb] = stats[t]; S[bb][a] = stats[t]; ++t; }

    const double M = (double)B_ * N_ * KNN;
    double wc[6];
#pragma unroll
    for (int j = 0; j < 6; ++j) wc[j] = (double)w1[j * COUT + c];
    const double b1c = (double)b1[c];

    double sw = 0.0;
#pragma unroll
    for (int j = 0; j < 6; ++j) sw += s[j] * wc[j];
    double mean = sw / M + b1c;

    double qq = 0.0;
#pragma unroll
    for (int a = 0; a < 6; ++a)
#pragma unroll
        for (int bb = 0; bb < 6; ++bb) qq += S[a][bb] * wc[a] * wc[bb];
    double ex2 = (qq + 2.0 * b1c * sw) / M + b1c * b1c;
    double var = ex2 - mean * mean;

    double sc = (double)gamma[c] / sqrt(var + (double)EPS_);
    double sh = (double)beta[c] - mean * sc;
    scale_shift[c]        = (float)sc;
    scale_shift[COUT + c] = (float)sh;
}

// ===========================================================================
// Kernel 3: fused edge->lin1->BN->ReLU->lin2->max via split-bf16 MFMA
// (unchanged, verified: wave-private LDS, no barriers, 24 MFMA/k-tile)
// ===========================================================================
typedef __attribute__((ext_vector_type(8))) short short8;
typedef __attribute__((ext_vector_type(4))) float f32x4;

__device__ __forceinline__ unsigned short f2bf_rn(float f) {
    unsigned u = __float_as_uint(f);
    unsigned lsb = (u >> 16) & 1u;
    return (unsigned short)((u + 0x7FFFu + lsb) >> 16);
}
__device__ __forceinline__ float bf2f(unsigned short h) {
    return __uint_as_float(((unsigned)h) << 16);
}

__global__ __launch_bounds__(256) void mlp_max_kernel(
    const float* __restrict__ x, const int* __restrict__ idx,
    const float* __restrict__ w1, const float* __restrict__ b1,
    const float* __restrict__ scale_shift,
    const float* __restrict__ w2, const float* __restrict__ b2,
    float* __restrict__ out)
{
    __shared__ __align__(16) unsigned short hbuf[4][2][16][136];

    const int tid  = threadIdx.x;
    const int wv   = tid >> 6;
    const int lane = tid & 63;
    const int g    = lane >> 4;      // 16-lane group (k-chunk select)
    const int r15  = lane & 15;      // row (A) / col (B,C) within tile

    const int R     = (blockIdx.x * 4 + wv) * 16;   // wave's first row
    const int bbase = (R >> 12) << 12;              // batch slab start row

    const int c  = lane;
    const float sc = scale_shift[c];
    const float sh = scale_shift[COUT + c];
    float w1p[6];
#pragma unroll
    for (int j = 0; j < 6; ++j) w1p[j] = w1[j * COUT + c] * sc;
    const float b1p = fmaf(b1[c], sc, sh);
    const float dw0 = w1p[0] - w1p[3];
    const float dw1 = w1p[1] - w1p[4];
    const float dw2 = w1p[2] - w1p[5];

    short8 Wh[2][4], Wl[2][4];
#pragma unroll
    for (int t = 0; t < 2; ++t)
#pragma unroll
        for (int n = 0; n < 4; ++n) {
            short8 hv, lv;
#pragma unroll
            for (int jj = 0; jj < 8; ++jj) {
                float w = w2[(t * 32 + g * 8 + jj) * COUT + n * 16 + r15];
                unsigned short hi = f2bf_rn(w);
                unsigned short lo = f2bf_rn(w - bf2f(hi));
                hv[jj] = (short)hi;
                lv[jj] = (short)lo;
            }
            Wh[t][n] = hv;
            Wl[t][n] = lv;
        }

    float base[16];
#pragma unroll
    for (int r = 0; r < 16; ++r) {
        const float* pi = x + (size_t)(R + r) * 3;
        float v = b1p;
        v = fmaf(pi[0], dw0, v);
        v = fmaf(pi[1], dw1, v);
        v = fmaf(pi[2], dw2, v);
        base[r] = v;
    }

    const int* idxp = idx + (size_t)R * KNN;

    f32x4 mx[4];
#pragma unroll
    for (int n = 0; n < 4; ++n) {
        mx[n][0] = -INFINITY; mx[n][1] = -INFINITY;
        mx[n][2] = -INFINITY; mx[n][3] = -INFINITY;
    }

    for (int k = 0; k < KNN; ++k) {
        unsigned short* hb = &hbuf[wv][k & 1][0][0];

#pragma unroll
        for (int r = 0; r < 16; ++r) {
            int j = idxp[r * KNN + k];                    // wave-uniform
            const float* pj = x + (size_t)(bbase + j) * 3;
            float h = base[r];
            h = fmaf(pj[0], w1p[3], h);
            h = fmaf(pj[1], w1p[4], h);
            h = fmaf(pj[2], w1p[5], h);
            h = fmaxf(h, 0.0f);
            unsigned short hi = f2bf_rn(h);
            unsigned short lo = f2bf_rn(h - bf2f(hi));
            hb[r * 136 + c]      = hi;
            hb[r * 136 + 64 + c] = lo;
        }

        const unsigned short* rpnt = hb + r15 * 136;
        short8 Ah0 = *(const short8*)(rpnt + g * 8);
        short8 Ah1 = *(const short8*)(rpnt + 32 + g * 8);
        short8 Al0 = *(const short8*)(rpnt + 64 + g * 8);
        short8 Al1 = *(const short8*)(rpnt + 96 + g * 8);

#pragma unroll
        for (int n = 0; n < 4; ++n) {
            f32x4 a = {0.0f, 0.0f, 0.0f, 0.0f};
            a = __builtin_amdgcn_mfma_f32_16x16x32_bf16(Ah0, Wh[0][n], a, 0, 0, 0);
            a = __builtin_amdgcn_mfma_f32_16x16x32_bf16(Ah1, Wh[1][n], a, 0, 0, 0);
            a = __builtin_amdgcn_mfma_f32_16x16x32_bf16(Al0, Wh[0][n], a, 0, 0, 0);
            a = __builtin_amdgcn_mfma_f32_16x16x32_bf16(Al1, Wh[1][n], a, 0, 0, 0);
            a = __builtin_amdgcn_mfma_f32_16x16x32_bf16(Ah0, Wl[0][n], a, 0, 0, 0);
            a = __builtin_amdgcn_mfma_f32_16x16x32_bf16(Ah1, Wl[1][n], a, 0, 0, 0);
            mx[n][0] = fmaxf(mx[n][0], a[0]);
            mx[n][1] = fmaxf(mx[n][1], a[1]);
            mx[n][2] = fmaxf(mx[n][2], a[2]);
            mx[n][3] = fmaxf(mx[n][3], a[3]);
        }
    }

    float b2v[4];
#pragma unroll
    for (int n = 0; n < 4; ++n) b2v[n] = b2[n * 16 + r15];
#pragma unroll
    for (int n = 0; n < 4; ++n)
#pragma unroll
        for (int rr = 0; rr < 4; ++rr)
            out[(size_t)(R + g * 4 + rr) * COUT + n * 16 + r15] =
                mx[n][rr] + b2v[n];
}

// ===========================================================================
extern "C" void kernel_launch(void* const* d_in, const int* in_sizes, int n_in,
                              void* d_out, int out_size, void* d_ws, size_t ws_size,
                              hipStream_t stream)
{
    const float* x     = (const float*)d_in[0];
    const float* w1    = (const float*)d_in[2];
    const float* b1    = (const float*)d_in[3];
    const float* gamma = (const float*)d_in[4];
    const float* beta  = (const float*)d_in[5];
    const float* w2    = (const float*)d_in[6];
    const float* b2    = (const float*)d_in[7];
    float* out = (float*)d_out;

    char*   ws          = (char*)d_ws;
    double* stats       = (double*)ws;
    float*  scale_shift = (float*)(ws + 256);
    int*    idx         = (int*)(ws + 1024);
    int*    perm        = (int*)(ws + 1024 + (size_t)B_ * N_ * KNN * 4);

    // one-time opt-in for >64KB dynamic LDS; host-side, graph-capture-safe.
    static int _lds_once = []() {
        (void)hipFuncSetAttribute((const void*)knn_f64_kernel,
                                  hipFuncAttributeMaxDynamicSharedMemorySize,
                                  131072);
        return 0;
    }();
    (void)_lds_once;

    hipMemsetAsync(stats, 0, 27 * sizeof(double), stream);
    morton_bucket_kernel<<<B_, 1024, 0, stream>>>(x, perm);
    knn_f64_kernel<<<dim3(32, 16), 512, 81920, stream>>>(x, perm, idx, stats);
    bn_prep_kernel<<<1, COUT, 0, stream>>>(stats, w1, b1, gamma, beta, scale_shift);
    mlp_max_kernel<<<(B_ * N_) / 64, 256, 0, stream>>>(x, idx, w1, b1, scale_shift,
                                                       w2, b2, out);
}

// Round 8
// 477.613 us; speedup vs baseline: 1.7049x; 1.7049x over previous
//
#include <hip/hip_runtime.h>
#include <math.h>
#include <float.h>

#define B_   16
#define N_   4096
#define CIN  3
#define COUT 64
#define KNN  20
#define EPS_ 1e-5

// ---------------------------------------------------------------------------
// Workspace layout (5.5MB proven-safe footprint):
//   [0,   216): double stats[27]    (Sum e[6], Sum e e^T upper-tri[21])
//   [256, 768): float scale[64], shift[64]
//   [1024, 1024 + B*N*KNN*4): int idx[B*N*KNN]           (5242880 B)
//   [5243904, +B*N*4): int perm[B*N]  (Morton row order)  (262144 B)
//
// r7 post-mortem: three knn filter restructures (r5/r6/r7) all regressed vs
// the r1 f64-heap scan (489/574/611 vs 356us) — the in-loop sorted-shift
// maintenance gets if-converted / latency-bound in ways the source can't
// control. knn is REVERTED to the r1-verbatim kernel (356us, verified).
// This round's experiment is confined to mlp_max_kernel: idx staged in LDS
// + 1-deep neighbor prefetch pipeline (T14 shape), wave-private throughout.
// ---------------------------------------------------------------------------

__device__ __forceinline__ unsigned expand10(unsigned v) {
    v = (v | (v << 16)) & 0x030000FFu;
    v = (v | (v << 8))  & 0x0300F00Fu;
    v = (v | (v << 4))  & 0x030C30C3u;
    v = (v | (v << 2))  & 0x09249249u;
    return v;
}
__device__ __forceinline__ unsigned quant10(float v) {
    int q = (int)((v + 4.0f) * 128.0f);
    return (unsigned)min(1023, max(0, q));
}

// ===========================================================================
// Kernel 0: per-batch Morton COUNTING sort (verbatim r1, verified)
// ===========================================================================
__global__ __launch_bounds__(1024) void morton_bucket_kernel(
    const float* __restrict__ x, int* __restrict__ perm)
{
    __shared__ int hist[1024];
    __shared__ int scanbuf[1024];
    __shared__ int offs[1024];
    const int b = blockIdx.x, tid = threadIdx.x;
    const float* xb = x + (size_t)b * N_ * CIN;

    hist[tid] = 0;
    __syncthreads();

    int keys[4];
#pragma unroll
    for (int i = 0; i < 4; ++i) {
        int p = tid + i * 1024;
        float v0 = xb[p * 3 + 0], v1 = xb[p * 3 + 1], v2 = xb[p * 3 + 2];
        unsigned m = (expand10(quant10(v0)) << 2) |
                     (expand10(quant10(v1)) << 1) |
                      expand10(quant10(v2));
        keys[i] = (int)(m >> 20);          // top 10 bits
        atomicAdd(&hist[keys[i]], 1);
    }
    __syncthreads();

    int v = hist[tid];
    scanbuf[tid] = v;
    __syncthreads();
    for (int off = 1; off < 1024; off <<= 1) {   // Hillis-Steele inclusive
        int t = (tid >= off) ? scanbuf[tid - off] : 0;
        __syncthreads();
        scanbuf[tid] += t;
        __syncthreads();
    }
    offs[tid] = scanbuf[tid] - v;                // exclusive base
    __syncthreads();

#pragma unroll
    for (int i = 0; i < 4; ++i) {
        int p = tid + i * 1024;
        int pos = atomicAdd(&offs[keys[i]], 1);
        perm[b * N_ + pos] = p;
    }
}

// ===========================================================================
// Kernel 1: exact-match KNN — VERBATIM round-1 kernel (356us, verified).
// f64-packed keys + sorted-shift insert; morton staging, mod-4 interleaved
// quarters, ball prefill, 509-stride shuffled scan, 2-round LDS merge, BN.
// ===========================================================================
__global__ __launch_bounds__(512) void knn_f64_kernel(
    const float* __restrict__ x, const int* __restrict__ perm,
    int* __restrict__ idx_out, double* __restrict__ stats)
{
    __shared__ __align__(16) char smem[65536];
    float4* pts = (float4*)smem;                 // {x,y,z,bitcast(j)}
    double* scr = (double*)smem;                 // merge-scratch view

    const int b    = blockIdx.y;
    const int tid  = threadIdx.x;
    const int wave = tid >> 6;
    const int lane = tid & 63;
    const int r    = wave >> 2;     // row-group 0..1
    const int q    = wave & 3;      // interleave class: positions p&3==q
    const float* xb = x + (size_t)b * N_ * CIN;

    for (int p = tid; p < N_; p += 512) {
        int j = perm[b * N_ + p];                // coalesced
        pts[p] = make_float4(xb[j * 3 + 0], xb[j * 3 + 1], xb[j * 3 + 2],
                             __int_as_float(j));
    }
    __syncthreads();

    const int rowg = blockIdx.x * 128 + r * 64;  // wave's first row pos
    const float4 xf = pts[rowg + lane];
    const int jrow  = __float_as_int(xf.w);
    const float sqi = __fadd_rn(__fadd_rn(__fmul_rn(xf.x, xf.x),
                                          __fmul_rn(xf.y, xf.y)),
                                __fmul_rn(xf.z, xf.z));

    auto mkkey = [&](float4 p) -> double {
        float sqj = __fadd_rn(__fadd_rn(__fmul_rn(p.x, p.x),
                                        __fmul_rn(p.y, p.y)),
                              __fmul_rn(p.z, p.z));
        float dot = __fadd_rn(__fadd_rn(__fmul_rn(xf.x, p.x),
                                        __fmul_rn(xf.y, p.y)),
                              __fmul_rn(xf.z, p.z));
        float d = __fsub_rn(__fadd_rn(sqi, sqj), __fmul_rn(2.0f, dot));
        unsigned u = __float_as_uint(d);
        unsigned s = u ^ (0x80000000u | (unsigned)((int)u >> 31));
        return fma((double)s, 4096.0,
                   (double)(unsigned)__float_as_int(p.w));
    };

    double bk[KNN];
#pragma unroll
    for (int k = 0; k < KNN; ++k) bk[k] = 1e300;     // sentinels (sorted)

    auto insert = [&](double key) {
        if (key < bk[KNN - 1]) {
            double m = key;                  // carries max(bk_old[i-1], key)
#pragma unroll
            for (int k = 0; k < KNN; ++k) {
                double old = bk[k];
                bk[k] = fmin(m, old);
                m     = fmax(old, m);
            }
        }
    };

    const int ta = rowg >> 2;            // wave-uniform anchor (SGPR math)
#pragma unroll
    for (int k = 0; k < KNN; ++k)
        insert(mkkey(pts[4 * ((ta + k) & 1023) + q]));

    for (int s = 0; s < 1024; s += 4) {
        int v0 = ((s + 0) * 509) & 1023;
        int v1 = ((s + 1) * 509) & 1023;
        int v2 = ((s + 2) * 509) & 1023;
        int v3 = ((s + 3) * 509) & 1023;
        float4 a0 = pts[4 * ((ta + v0) & 1023) + q];
        float4 a1 = pts[4 * ((ta + v1) & 1023) + q];
        float4 a2 = pts[4 * ((ta + v2) & 1023) + q];
        float4 a3 = pts[4 * ((ta + v3) & 1023) + q];
        double k0 = (v0 < 20) ? 1e300 : mkkey(a0);
        double k1 = (v1 < 20) ? 1e300 : mkkey(a1);
        double k2 = (v2 < 20) ? 1e300 : mkkey(a2);
        double k3 = (v3 < 20) ? 1e300 : mkkey(a3);
        double w = bk[KNN - 1];          // stale for the check: over-enters only
        if ((k0 < w) | (k1 < w) | (k2 < w) | (k3 < w)) {
            insert(k0); insert(k1); insert(k2); insert(k3);
        }
    }
    __syncthreads();    // scans done; pts dead (xf in regs) -> scr valid

    if (q & 1) {
        int base = ((r * 2 + (q >> 1)) * 64 + lane) * KNN;
#pragma unroll
        for (int k = 0; k < KNN; ++k) scr[base + k] = bk[k];
    }
    __syncthreads();
    if (!(q & 1)) {                 // q0 absorbs q1; q2 absorbs q3
        int base = ((r * 2 + (q >> 1)) * 64 + lane) * KNN;
#pragma unroll
        for (int k = 0; k < KNN; ++k) insert(scr[base + k]);
    }
    __syncthreads();
    if (q == 2) {
        int base = ((r * 2 + 1) * 64 + lane) * KNN;
#pragma unroll
        for (int k = 0; k < KNN; ++k) scr[base + k] = bk[k];
    }
    __syncthreads();
    if (q == 0) {
        int base = ((r * 2 + 1) * 64 + lane) * KNN;
#pragma unroll
        for (int k = 0; k < KNN; ++k) insert(scr[base + k]);

        const long long row = (long long)b * N_ + jrow;
        int bi[KNN];
#pragma unroll
        for (int k = 0; k < KNN; ++k) {
            double sp = trunc(bk[k] * (1.0 / 4096.0));
            bi[k] = (int)(bk[k] - sp * 4096.0);
        }
#pragma unroll
        for (int k = 0; k < KNN; ++k) idx_out[row * KNN + k] = bi[k];

        float acc[27];
#pragma unroll
        for (int t = 0; t < 27; ++t) acc[t] = 0.0f;
#pragma unroll
        for (int k = 0; k < KNN; ++k) {
            const float* pj = xb + bi[k] * 3;
            float e[6] = { xf.x, xf.y, xf.z,
                           pj[0] - xf.x, pj[1] - xf.y, pj[2] - xf.z };
            int t = 6;
#pragma unroll
            for (int a = 0; a < 6; ++a) {
                acc[a] += e[a];
#pragma unroll
                for (int bb = a; bb < 6; ++bb) acc[t++] += e[a] * e[bb];
            }
        }
#pragma unroll
        for (int t = 0; t < 27; ++t) {
            float v = acc[t];
            v += __shfl_down(v, 32); v += __shfl_down(v, 16);
            v += __shfl_down(v, 8);  v += __shfl_down(v, 4);
            v += __shfl_down(v, 2);  v += __shfl_down(v, 1);
            acc[t] = v;
        }
        if (lane == 0) {
#pragma unroll
            for (int t = 0; t < 27; ++t) atomicAdd(&stats[t], (double)acc[t]);
        }
    }
}

// ===========================================================================
// Kernel 2: fold stats -> per-channel scale/shift (unchanged, verified)
// ===========================================================================
__global__ void bn_prep_kernel(
    const double* __restrict__ stats,
    const float* __restrict__ w1, const float* __restrict__ b1,
    const float* __restrict__ gamma, const float* __restrict__ beta,
    float* __restrict__ scale_shift)
{
    const int c = threadIdx.x;
    double s[6], S[6][6];
#pragma unroll
    for (int a = 0; a < 6; ++a) s[a] = stats[a];
    int t = 6;
#pragma unroll
    for (int a = 0; a < 6; ++a)
#pragma unroll
        for (int bb = a; bb < 6; ++bb) { S[a][bb] = stats[t]; S[bb][a] = stats[t]; ++t; }

    const double M = (double)B_ * N_ * KNN;
    double wc[6];
#pragma unroll
    for (int j = 0; j < 6; ++j) wc[j] = (double)w1[j * COUT + c];
    const double b1c = (double)b1[c];

    double sw = 0.0;
#pragma unroll
    for (int j = 0; j < 6; ++j) sw += s[j] * wc[j];
    double mean = sw / M + b1c;

    double qq = 0.0;
#pragma unroll
    for (int a = 0; a < 6; ++a)
#pragma unroll
        for (int bb = 0; bb < 6; ++bb) qq += S[a][bb] * wc[a] * wc[bb];
    double ex2 = (qq + 2.0 * b1c * sw) / M + b1c * b1c;
    double var = ex2 - mean * mean;

    double sc = (double)gamma[c] / sqrt(var + (double)EPS_);
    double sh = (double)beta[c] - mean * sc;
    scale_shift[c]        = (float)sc;
    scale_shift[COUT + c] = (float)sh;
}

// ===========================================================================
// Kernel 3: fused edge->lin1->BN->ReLU->lin2->max via split-bf16 MFMA.
// r8 change (THIS round's experiment; arithmetic unchanged, wave-private):
//   - idx block (320 ints/wave) staged into LDS once, coalesced: removes
//     the 200cy idx-load head of the per-(row,k) gather chain.
//   - neighbor coords prefetched one k ahead into px/py/pz[16]: the 48
//     independent global loads for k+1 are issued before the MFMA block of
//     k, hiding HBM latency under MFMA+VALU (T14 async-split shape).
// ===========================================================================
typedef __attribute__((ext_vector_type(8))) short short8;
typedef __attribute__((ext_vector_type(4))) float f32x4;

__device__ __forceinline__ unsigned short f2bf_rn(float f) {
    unsigned u = __float_as_uint(f);
    unsigned lsb = (u >> 16) & 1u;
    return (unsigned short)((u + 0x7FFFu + lsb) >> 16);
}
__device__ __forceinline__ float bf2f(unsigned short h) {
    return __uint_as_float(((unsigned)h) << 16);
}

__global__ __launch_bounds__(256) void mlp_max_kernel(
    const float* __restrict__ x, const int* __restrict__ idx,
    const float* __restrict__ w1, const float* __restrict__ b1,
    const float* __restrict__ scale_shift,
    const float* __restrict__ w2, const float* __restrict__ b2,
    float* __restrict__ out)
{
    __shared__ __align__(16) unsigned short hbuf[4][2][16][136];  // 34.8KB
    __shared__ int idxs[4][320];                                  // +5KB

    const int tid  = threadIdx.x;
    const int wv   = tid >> 6;
    const int lane = tid & 63;
    const int g    = lane >> 4;      // 16-lane group (k-chunk select)
    const int r15  = lane & 15;      // row (A) / col (B,C) within tile

    const int R     = (blockIdx.x * 4 + wv) * 16;   // wave's first row
    const int bbase = (R >> 12) << 12;              // batch slab start row

    // ---- stage this wave's idx block into LDS (coalesced, wave-private) --
    {
        const int* ip = idx + (size_t)R * KNN;
#pragma unroll
        for (int i = 0; i < 5; ++i)
            idxs[wv][lane + i * 64] = ip[lane + i * 64];
    }

    const int c  = lane;
    const float sc = scale_shift[c];
    const float sh = scale_shift[COUT + c];
    float w1p[6];
#pragma unroll
    for (int j = 0; j < 6; ++j) w1p[j] = w1[j * COUT + c] * sc;
    const float b1p = fmaf(b1[c], sc, sh);
    const float dw0 = w1p[0] - w1p[3];
    const float dw1 = w1p[1] - w1p[4];
    const float dw2 = w1p[2] - w1p[5];

    short8 Wh[2][4], Wl[2][4];
#pragma unroll
    for (int t = 0; t < 2; ++t)
#pragma unroll
        for (int n = 0; n < 4; ++n) {
            short8 hv, lv;
#pragma unroll
            for (int jj = 0; jj < 8; ++jj) {
                float w = w2[(t * 32 + g * 8 + jj) * COUT + n * 16 + r15];
                unsigned short hi = f2bf_rn(w);
                unsigned short lo = f2bf_rn(w - bf2f(hi));
                hv[jj] = (short)hi;
                lv[jj] = (short)lo;
            }
            Wh[t][n] = hv;
            Wl[t][n] = lv;
        }

    float base[16];
#pragma unroll
    for (int r = 0; r < 16; ++r) {
        const float* pi = x + (size_t)(R + r) * 3;
        float v = b1p;
        v = fmaf(pi[0], dw0, v);
        v = fmaf(pi[1], dw1, v);
        v = fmaf(pi[2], dw2, v);
        base[r] = v;
    }

    // ---- prefetch k=0 neighbor coords ----
    float px[16], py[16], pz[16];
#pragma unroll
    for (int r = 0; r < 16; ++r) {
        int j = idxs[wv][r * KNN];                    // wave-uniform (LDS)
        const float* pj = x + (size_t)(bbase + j) * 3;
        px[r] = pj[0]; py[r] = pj[1]; pz[r] = pj[2];
    }

    f32x4 mx[4];
#pragma unroll
    for (int n = 0; n < 4; ++n) {
        mx[n][0] = -INFINITY; mx[n][1] = -INFINITY;
        mx[n][2] = -INFINITY; mx[n][3] = -INFINITY;
    }

    for (int k = 0; k < KNN; ++k) {
        unsigned short* hb = &hbuf[wv][k & 1][0][0];

        // consume prefetched coords -> h tile (bf16 hi/lo) in LDS
#pragma unroll
        for (int r = 0; r < 16; ++r) {
            float h = base[r];
            h = fmaf(px[r], w1p[3], h);
            h = fmaf(py[r], w1p[4], h);
            h = fmaf(pz[r], w1p[5], h);
            h = fmaxf(h, 0.0f);
            unsigned short hi = f2bf_rn(h);
            unsigned short lo = f2bf_rn(h - bf2f(hi));
            hb[r * 136 + c]      = hi;
            hb[r * 136 + 64 + c] = lo;
        }

        // prefetch k+1: 48 independent loads issued BEFORE the MFMA block
        if (k + 1 < KNN) {
#pragma unroll
            for (int r = 0; r < 16; ++r) {
                int j = idxs[wv][r * KNN + k + 1];     // LDS, wave-uniform
                const float* pj = x + (size_t)(bbase + j) * 3;
                px[r] = pj[0]; py[r] = pj[1]; pz[r] = pj[2];
            }
        }

        const unsigned short* rpnt = hb + r15 * 136;
        short8 Ah0 = *(const short8*)(rpnt + g * 8);
        short8 Ah1 = *(const short8*)(rpnt + 32 + g * 8);
        short8 Al0 = *(const short8*)(rpnt + 64 + g * 8);
        short8 Al1 = *(const short8*)(rpnt + 96 + g * 8);

#pragma unroll
        for (int n = 0; n < 4; ++n) {
            f32x4 a = {0.0f, 0.0f, 0.0f, 0.0f};
            a = __builtin_amdgcn_mfma_f32_16x16x32_bf16(Ah0, Wh[0][n], a, 0, 0, 0);
            a = __builtin_amdgcn_mfma_f32_16x16x32_bf16(Ah1, Wh[1][n], a, 0, 0, 0);
            a = __builtin_amdgcn_mfma_f32_16x16x32_bf16(Al0, Wh[0][n], a, 0, 0, 0);
            a = __builtin_amdgcn_mfma_f32_16x16x32_bf16(Al1, Wh[1][n], a, 0, 0, 0);
            a = __builtin_amdgcn_mfma_f32_16x16x32_bf16(Ah0, Wl[0][n], a, 0, 0, 0);
            a = __builtin_amdgcn_mfma_f32_16x16x32_bf16(Ah1, Wl[1][n], a, 0, 0, 0);
            mx[n][0] = fmaxf(mx[n][0], a[0]);
            mx[n][1] = fmaxf(mx[n][1], a[1]);
            mx[n][2] = fmaxf(mx[n][2], a[2]);
            mx[n][3] = fmaxf(mx[n][3], a[3]);
        }
    }

    float b2v[4];
#pragma unroll
    for (int n = 0; n < 4; ++n) b2v[n] = b2[n * 16 + r15];
#pragma unroll
    for (int n = 0; n < 4; ++n)
#pragma unroll
        for (int rr = 0; rr < 4; ++rr)
            out[(size_t)(R + g * 4 + rr) * COUT + n * 16 + r15] =
                mx[n][rr] + b2v[n];
}

// ===========================================================================
extern "C" void kernel_launch(void* const* d_in, const int* in_sizes, int n_in,
                              void* d_out, int out_size, void* d_ws, size_t ws_size,
                              hipStream_t stream)
{
    const float* x     = (const float*)d_in[0];
    const float* w1    = (const float*)d_in[2];
    const float* b1    = (const float*)d_in[3];
    const float* gamma = (const float*)d_in[4];
    const float* beta  = (const float*)d_in[5];
    const float* w2    = (const float*)d_in[6];
    const float* b2    = (const float*)d_in[7];
    float* out = (float*)d_out;

    char*   ws          = (char*)d_ws;
    double* stats       = (double*)ws;
    float*  scale_shift = (float*)(ws + 256);
    int*    idx         = (int*)(ws + 1024);
    int*    perm        = (int*)(ws + 1024 + (size_t)B_ * N_ * KNN * 4);

    hipMemsetAsync(stats, 0, 27 * sizeof(double), stream);
    morton_bucket_kernel<<<B_, 1024, 0, stream>>>(x, perm);
    knn_f64_kernel<<<dim3(32, 16), 512, 0, stream>>>(x, perm, idx, stats);
    bn_prep_kernel<<<1, COUT, 0, stream>>>(stats, w1, b1, gamma, beta, scale_shift);
    mlp_max_kernel<<<(B_ * N_) / 64, 256, 0, stream>>>(x, idx, w1, b1, scale_shift,
                                                       w2, b2, out);
}

// Round 9
// 460.709 us; speedup vs baseline: 1.7674x; 1.0367x over previous
//
#include <hip/hip_runtime.h>
#include <math.h>
#include <float.h>

#define B_   16
#define N_   4096
#define CIN  3
#define COUT 64
#define KNN  20
#define EPS_ 1e-5

// ---------------------------------------------------------------------------
// Workspace layout (5.5MB proven-safe footprint):
//   [0,   216): double stats[27]    (Sum e[6], Sum e e^T upper-tri[21])
//   [256, 768): float scale[64], shift[64]
//   [1024, 1024 + B*N*KNN*4): int idx[B*N*KNN]           (5242880 B)
//   [5243904, +B*N*4): int perm[B*N]  (Morton row order)  (262144 B)
//
// r9 change (knn, micro-opt INSIDE the verified r1 loop — no restructure):
//   * pts.w now carries sqj (bit-identical staged expression); orig index
//     lives in j16[4096] (LDS, 72KB total dynamic, still 2 blocks/CU).
//     mkd: 13 -> 8 f32 ops per candidate.
//   * trigger compares sortable-u32 s_i <= s19 (shadow of bk[19]'s s-part,
//     refreshed only in triggered bodies -> exact between bodies; <= over-
//     enters on s-ties exactly like r1's stale-w check; insert re-checks
//     the full f64 key). f64 key build moved INSIDE the ~55%-rate body.
//   Selection provably identical: same candidates, same exact keys, same
//   verified insert/merge/extraction machinery.
// ---------------------------------------------------------------------------

__device__ __forceinline__ unsigned expand10(unsigned v) {
    v = (v | (v << 16)) & 0x030000FFu;
    v = (v | (v << 8))  & 0x0300F00Fu;
    v = (v | (v << 4))  & 0x030C30C3u;
    v = (v | (v << 2))  & 0x09249249u;
    return v;
}
__device__ __forceinline__ unsigned quant10(float v) {
    int q = (int)((v + 4.0f) * 128.0f);
    return (unsigned)min(1023, max(0, q));
}

// ===========================================================================
// Kernel 0: per-batch Morton COUNTING sort (verbatim, verified)
// ===========================================================================
__global__ __launch_bounds__(1024) void morton_bucket_kernel(
    const float* __restrict__ x, int* __restrict__ perm)
{
    __shared__ int hist[1024];
    __shared__ int scanbuf[1024];
    __shared__ int offs[1024];
    const int b = blockIdx.x, tid = threadIdx.x;
    const float* xb = x + (size_t)b * N_ * CIN;

    hist[tid] = 0;
    __syncthreads();

    int keys[4];
#pragma unroll
    for (int i = 0; i < 4; ++i) {
        int p = tid + i * 1024;
        float v0 = xb[p * 3 + 0], v1 = xb[p * 3 + 1], v2 = xb[p * 3 + 2];
        unsigned m = (expand10(quant10(v0)) << 2) |
                     (expand10(quant10(v1)) << 1) |
                      expand10(quant10(v2));
        keys[i] = (int)(m >> 20);          // top 10 bits
        atomicAdd(&hist[keys[i]], 1);
    }
    __syncthreads();

    int v = hist[tid];
    scanbuf[tid] = v;
    __syncthreads();
    for (int off = 1; off < 1024; off <<= 1) {   // Hillis-Steele inclusive
        int t = (tid >= off) ? scanbuf[tid - off] : 0;
        __syncthreads();
        scanbuf[tid] += t;
        __syncthreads();
    }
    offs[tid] = scanbuf[tid] - v;                // exclusive base
    __syncthreads();

#pragma unroll
    for (int i = 0; i < 4; ++i) {
        int p = tid + i * 1024;
        int pos = atomicAdd(&offs[keys[i]], 1);
        perm[b * N_ + pos] = p;
    }
}

// ===========================================================================
// Kernel 1: exact-match KNN — r1-verbatim structure (356us verified) with
// the r9 micro-opts described above. Order, trigger semantics (stale/over-
// enter), insert, merge, extraction, BN stats all unchanged.
// ===========================================================================
__global__ __launch_bounds__(512) void knn_f64_kernel(
    const float* __restrict__ x, const int* __restrict__ perm,
    int* __restrict__ idx_out, double* __restrict__ stats)
{
    extern __shared__ __align__(16) char smem[];
    float4* pts = (float4*)smem;                            // {x,y,z,sqj}
    unsigned short* j16 = (unsigned short*)(smem + 65536);  // [4096] orig idx
    double* scr = (double*)smem;                            // merge view

    const int b    = blockIdx.y;
    const int tid  = threadIdx.x;
    const int wave = tid >> 6;
    const int lane = tid & 63;
    const int r    = wave >> 2;     // row-group 0..1
    const int q    = wave & 3;      // interleave class: positions p&3==q
    const float* xb = x + (size_t)b * N_ * CIN;

    for (int p = tid; p < N_; p += 512) {
        int j = perm[b * N_ + p];                // coalesced
        float v0 = xb[j * 3 + 0], v1 = xb[j * 3 + 1], v2 = xb[j * 3 + 2];
        // bit-identical to the reference's per-point sq expression
        float sq = __fadd_rn(__fadd_rn(__fmul_rn(v0, v0),
                                       __fmul_rn(v1, v1)),
                             __fmul_rn(v2, v2));
        pts[p] = make_float4(v0, v1, v2, sq);
        j16[p] = (unsigned short)j;
    }
    __syncthreads();

    const int rowg = blockIdx.x * 128 + r * 64;  // wave's first row pos
    const float4 xf = pts[rowg + lane];
    const int jrow  = j16[rowg + lane];
    const float sqi = xf.w;                      // staged, bit-identical

    // exact f32 distance (expansion form), sqj from the staged .w
    auto mkd = [&](float4 p) -> float {
        float dot = __fadd_rn(__fadd_rn(__fmul_rn(xf.x, p.x),
                                        __fmul_rn(xf.y, p.y)),
                              __fmul_rn(xf.z, p.z));
        return __fsub_rn(__fadd_rn(sqi, p.w), __fmul_rn(2.0f, dot));
    };
    auto sortable = [&](float d) -> unsigned {
        unsigned u = __float_as_uint(d);
        return u ^ (0x80000000u | (unsigned)((int)u >> 31));
    };

    double bk[KNN];
#pragma unroll
    for (int k = 0; k < KNN; ++k) bk[k] = 1e300;     // sentinels (sorted)

    auto insert = [&](double key) {                  // VERBATIM verified
        if (key < bk[KNN - 1]) {
            double m = key;                  // carries max(bk_old[i-1], key)
#pragma unroll
            for (int k = 0; k < KNN; ++k) {
                double old = bk[k];
                bk[k] = fmin(m, old);
                m     = fmax(old, m);
            }
        }
    };

    const int ta = rowg >> 2;            // wave-uniform anchor (SGPR math)
#pragma unroll
    for (int k = 0; k < KNN; ++k) {
        int p = 4 * ((ta + k) & 1023) + q;
        float4 a = pts[p];
        insert(fma((double)sortable(mkd(a)), 4096.0,
                   (double)(unsigned)j16[p]));
    }

    // shadow of bk[19]'s u32 s-part; bk = s*4096+j is integer-exact in f64.
    // Refreshed only where bk can change (inside triggered bodies) -> exact
    // between bodies; "<=" over-enters on s-ties (insert re-checks full key).
    unsigned s19 = (unsigned)trunc(bk[KNN - 1] * (1.0 / 4096.0));

    for (int s = 0; s < 1024; s += 4) {
        int v0 = ((s + 0) * 509) & 1023;
        int v1 = ((s + 1) * 509) & 1023;
        int v2 = ((s + 2) * 509) & 1023;
        int v3 = ((s + 3) * 509) & 1023;
        int p0 = 4 * ((ta + v0) & 1023) + q;
        int p1 = 4 * ((ta + v1) & 1023) + q;
        int p2 = 4 * ((ta + v2) & 1023) + q;
        int p3 = 4 * ((ta + v3) & 1023) + q;
        float4 a0 = pts[p0];
        float4 a1 = pts[p1];
        float4 a2 = pts[p2];
        float4 a3 = pts[p3];
        unsigned j0 = j16[p0], j1 = j16[p1], j2 = j16[p2], j3 = j16[p3];
        unsigned t0 = sortable(mkd(a0));
        unsigned t1 = sortable(mkd(a1));
        unsigned t2 = sortable(mkd(a2));
        unsigned t3 = sortable(mkd(a3));
        // prefill positions masked (as r1's v<20 sentinel): 0xFFFFFFFF*4096
        // exceeds any real key (s <= ~0xC6000000), so it can never insert.
        t0 = (v0 < 20) ? 0xFFFFFFFFu : t0;
        t1 = (v1 < 20) ? 0xFFFFFFFFu : t1;
        t2 = (v2 < 20) ? 0xFFFFFFFFu : t2;
        t3 = (v3 < 20) ? 0xFFFFFFFFu : t3;
        if ((t0 <= s19) | (t1 <= s19) | (t2 <= s19) | (t3 <= s19)) {
            insert(fma((double)t0, 4096.0, (double)j0));
            insert(fma((double)t1, 4096.0, (double)j1));
            insert(fma((double)t2, 4096.0, (double)j2));
            insert(fma((double)t3, 4096.0, (double)j3));
            s19 = (unsigned)trunc(bk[KNN - 1] * (1.0 / 4096.0));
        }
    }
    __syncthreads();    // scans done; pts dead (xf in regs) -> scr valid

    if (q & 1) {
        int base = ((r * 2 + (q >> 1)) * 64 + lane) * KNN;
#pragma unroll
        for (int k = 0; k < KNN; ++k) scr[base + k] = bk[k];
    }
    __syncthreads();
    if (!(q & 1)) {                 // q0 absorbs q1; q2 absorbs q3
        int base = ((r * 2 + (q >> 1)) * 64 + lane) * KNN;
#pragma unroll
        for (int k = 0; k < KNN; ++k) insert(scr[base + k]);
    }
    __syncthreads();
    if (q == 2) {
        int base = ((r * 2 + 1) * 64 + lane) * KNN;
#pragma unroll
        for (int k = 0; k < KNN; ++k) scr[base + k] = bk[k];
    }
    __syncthreads();
    if (q == 0) {
        int base = ((r * 2 + 1) * 64 + lane) * KNN;
#pragma unroll
        for (int k = 0; k < KNN; ++k) insert(scr[base + k]);

        const long long row = (long long)b * N_ + jrow;
        int bi[KNN];
#pragma unroll
        for (int k = 0; k < KNN; ++k) {
            double sp = trunc(bk[k] * (1.0 / 4096.0));
            bi[k] = (int)(bk[k] - sp * 4096.0);
        }
#pragma unroll
        for (int k = 0; k < KNN; ++k) idx_out[row * KNN + k] = bi[k];

        float acc[27];
#pragma unroll
        for (int t = 0; t < 27; ++t) acc[t] = 0.0f;
#pragma unroll
        for (int k = 0; k < KNN; ++k) {
            const float* pj = xb + bi[k] * 3;
            float e[6] = { xf.x, xf.y, xf.z,
                           pj[0] - xf.x, pj[1] - xf.y, pj[2] - xf.z };
            int t = 6;
#pragma unroll
            for (int a = 0; a < 6; ++a) {
                acc[a] += e[a];
#pragma unroll
                for (int bb = a; bb < 6; ++bb) acc[t++] += e[a] * e[bb];
            }
        }
#pragma unroll
        for (int t = 0; t < 27; ++t) {
            float v = acc[t];
            v += __shfl_down(v, 32); v += __shfl_down(v, 16);
            v += __shfl_down(v, 8);  v += __shfl_down(v, 4);
            v += __shfl_down(v, 2);  v += __shfl_down(v, 1);
            acc[t] = v;
        }
        if (lane == 0) {
#pragma unroll
            for (int t = 0; t < 27; ++t) atomicAdd(&stats[t], (double)acc[t]);
        }
    }
}

// ===========================================================================
// Kernel 2: fold stats -> per-channel scale/shift (unchanged, verified)
// ===========================================================================
__global__ void bn_prep_kernel(
    const double* __restrict__ stats,
    const float* __restrict__ w1, const float* __restrict__ b1,
    const float* __restrict__ gamma, const float* __restrict__ beta,
    float* __restrict__ scale_shift)
{
    const int c = threadIdx.x;
    double s[6], S[6][6];
#pragma unroll
    for (int a = 0; a < 6; ++a) s[a] = stats[a];
    int t = 6;
#pragma unroll
    for (int a = 0; a < 6; ++a)
#pragma unroll
        for (int bb = a; bb < 6; ++bb) { S[a][bb] = stats[t]; S[bb][a] = stats[t]; ++t; }

    const double M = (double)B_ * N_ * KNN;
    double wc[6];
#pragma unroll
    for (int j = 0; j < 6; ++j) wc[j] = (double)w1[j * COUT + c];
    const double b1c = (double)b1[c];

    double sw = 0.0;
#pragma unroll
    for (int j = 0; j < 6; ++j) sw += s[j] * wc[j];
    double mean = sw / M + b1c;

    double qq = 0.0;
#pragma unroll
    for (int a = 0; a < 6; ++a)
#pragma unroll
        for (int bb = 0; bb < 6; ++bb) qq += S[a][bb] * wc[a] * wc[bb];
    double ex2 = (qq + 2.0 * b1c * sw) / M + b1c * b1c;
    double var = ex2 - mean * mean;

    double sc = (double)gamma[c] / sqrt(var + (double)EPS_);
    double sh = (double)beta[c] - mean * sc;
    scale_shift[c]        = (float)sc;
    scale_shift[COUT + c] = (float)sh;
}

// ===========================================================================
// Kernel 3: fused edge->lin1->BN->ReLU->lin2->max via split-bf16 MFMA.
// (verbatim r8, verified: idx staged in LDS + 1-deep neighbor prefetch,
// wave-private, no barriers, 24 MFMA/k-tile)
// ===========================================================================
typedef __attribute__((ext_vector_type(8))) short short8;
typedef __attribute__((ext_vector_type(4))) float f32x4;

__device__ __forceinline__ unsigned short f2bf_rn(float f) {
    unsigned u = __float_as_uint(f);
    unsigned lsb = (u >> 16) & 1u;
    return (unsigned short)((u + 0x7FFFu + lsb) >> 16);
}
__device__ __forceinline__ float bf2f(unsigned short h) {
    return __uint_as_float(((unsigned)h) << 16);
}

__global__ __launch_bounds__(256) void mlp_max_kernel(
    const float* __restrict__ x, const int* __restrict__ idx,
    const float* __restrict__ w1, const float* __restrict__ b1,
    const float* __restrict__ scale_shift,
    const float* __restrict__ w2, const float* __restrict__ b2,
    float* __restrict__ out)
{
    __shared__ __align__(16) unsigned short hbuf[4][2][16][136];  // 34.8KB
    __shared__ int idxs[4][320];                                  // +5KB

    const int tid  = threadIdx.x;
    const int wv   = tid >> 6;
    const int lane = tid & 63;
    const int g    = lane >> 4;      // 16-lane group (k-chunk select)
    const int r15  = lane & 15;      // row (A) / col (B,C) within tile

    const int R     = (blockIdx.x * 4 + wv) * 16;   // wave's first row
    const int bbase = (R >> 12) << 12;              // batch slab start row

    // ---- stage this wave's idx block into LDS (coalesced, wave-private) --
    {
        const int* ip = idx + (size_t)R * KNN;
#pragma unroll
        for (int i = 0; i < 5; ++i)
            idxs[wv][lane + i * 64] = ip[lane + i * 64];
    }

    const int c  = lane;
    const float sc = scale_shift[c];
    const float sh = scale_shift[COUT + c];
    float w1p[6];
#pragma unroll
    for (int j = 0; j < 6; ++j) w1p[j] = w1[j * COUT + c] * sc;
    const float b1p = fmaf(b1[c], sc, sh);
    const float dw0 = w1p[0] - w1p[3];
    const float dw1 = w1p[1] - w1p[4];
    const float dw2 = w1p[2] - w1p[5];

    short8 Wh[2][4], Wl[2][4];
#pragma unroll
    for (int t = 0; t < 2; ++t)
#pragma unroll
        for (int n = 0; n < 4; ++n) {
            short8 hv, lv;
#pragma unroll
            for (int jj = 0; jj < 8; ++jj) {
                float w = w2[(t * 32 + g * 8 + jj) * COUT + n * 16 + r15];
                unsigned short hi = f2bf_rn(w);
                unsigned short lo = f2bf_rn(w - bf2f(hi));
                hv[jj] = (short)hi;
                lv[jj] = (short)lo;
            }
            Wh[t][n] = hv;
            Wl[t][n] = lv;
        }

    float base[16];
#pragma unroll
    for (int r = 0; r < 16; ++r) {
        const float* pi = x + (size_t)(R + r) * 3;
        float v = b1p;
        v = fmaf(pi[0], dw0, v);
        v = fmaf(pi[1], dw1, v);
        v = fmaf(pi[2], dw2, v);
        base[r] = v;
    }

    // ---- prefetch k=0 neighbor coords ----
    float px[16], py[16], pz[16];
#pragma unroll
    for (int r = 0; r < 16; ++r) {
        int j = idxs[wv][r * KNN];                    // wave-uniform (LDS)
        const float* pj = x + (size_t)(bbase + j) * 3;
        px[r] = pj[0]; py[r] = pj[1]; pz[r] = pj[2];
    }

    f32x4 mx[4];
#pragma unroll
    for (int n = 0; n < 4; ++n) {
        mx[n][0] = -INFINITY; mx[n][1] = -INFINITY;
        mx[n][2] = -INFINITY; mx[n][3] = -INFINITY;
    }

    for (int k = 0; k < KNN; ++k) {
        unsigned short* hb = &hbuf[wv][k & 1][0][0];

        // consume prefetched coords -> h tile (bf16 hi/lo) in LDS
#pragma unroll
        for (int r = 0; r < 16; ++r) {
            float h = base[r];
            h = fmaf(px[r], w1p[3], h);
            h = fmaf(py[r], w1p[4], h);
            h = fmaf(pz[r], w1p[5], h);
            h = fmaxf(h, 0.0f);
            unsigned short hi = f2bf_rn(h);
            unsigned short lo = f2bf_rn(h - bf2f(hi));
            hb[r * 136 + c]      = hi;
            hb[r * 136 + 64 + c] = lo;
        }

        // prefetch k+1: 48 independent loads issued BEFORE the MFMA block
        if (k + 1 < KNN) {
#pragma unroll
            for (int r = 0; r < 16; ++r) {
                int j = idxs[wv][r * KNN + k + 1];     // LDS, wave-uniform
                const float* pj = x + (size_t)(bbase + j) * 3;
                px[r] = pj[0]; py[r] = pj[1]; pz[r] = pj[2];
            }
        }

        const unsigned short* rpnt = hb + r15 * 136;
        short8 Ah0 = *(const short8*)(rpnt + g * 8);
        short8 Ah1 = *(const short8*)(rpnt + 32 + g * 8);
        short8 Al0 = *(const short8*)(rpnt + 64 + g * 8);
        short8 Al1 = *(const short8*)(rpnt + 96 + g * 8);

#pragma unroll
        for (int n = 0; n < 4; ++n) {
            f32x4 a = {0.0f, 0.0f, 0.0f, 0.0f};
            a = __builtin_amdgcn_mfma_f32_16x16x32_bf16(Ah0, Wh[0][n], a, 0, 0, 0);
            a = __builtin_amdgcn_mfma_f32_16x16x32_bf16(Ah1, Wh[1][n], a, 0, 0, 0);
            a = __builtin_amdgcn_mfma_f32_16x16x32_bf16(Al0, Wh[0][n], a, 0, 0, 0);
            a = __builtin_amdgcn_mfma_f32_16x16x32_bf16(Al1, Wh[1][n], a, 0, 0, 0);
            a = __builtin_amdgcn_mfma_f32_16x16x32_bf16(Ah0, Wl[0][n], a, 0, 0, 0);
            a = __builtin_amdgcn_mfma_f32_16x16x32_bf16(Ah1, Wl[1][n], a, 0, 0, 0);
            mx[n][0] = fmaxf(mx[n][0], a[0]);
            mx[n][1] = fmaxf(mx[n][1], a[1]);
            mx[n][2] = fmaxf(mx[n][2], a[2]);
            mx[n][3] = fmaxf(mx[n][3], a[3]);
        }
    }

    float b2v[4];
#pragma unroll
    for (int n = 0; n < 4; ++n) b2v[n] = b2[n * 16 + r15];
#pragma unroll
    for (int n = 0; n < 4; ++n)
#pragma unroll
        for (int rr = 0; rr < 4; ++rr)
            out[(size_t)(R + g * 4 + rr) * COUT + n * 16 + r15] =
                mx[n][rr] + b2v[n];
}

// ===========================================================================
extern "C" void kernel_launch(void* const* d_in, const int* in_sizes, int n_in,
                              void* d_out, int out_size, void* d_ws, size_t ws_size,
                              hipStream_t stream)
{
    const float* x     = (const float*)d_in[0];
    const float* w1    = (const float*)d_in[2];
    const float* b1    = (const float*)d_in[3];
    const float* gamma = (const float*)d_in[4];
    const float* beta  = (const float*)d_in[5];
    const float* w2    = (const float*)d_in[6];
    const float* b2    = (const float*)d_in[7];
    float* out = (float*)d_out;

    char*   ws          = (char*)d_ws;
    double* stats       = (double*)ws;
    float*  scale_shift = (float*)(ws + 256);
    int*    idx         = (int*)(ws + 1024);
    int*    perm        = (int*)(ws + 1024 + (size_t)B_ * N_ * KNN * 4);

    // one-time opt-in for >64KB dynamic LDS; host-side, graph-capture-safe.
    static int _lds_once = []() {
        (void)hipFuncSetAttribute((const void*)knn_f64_kernel,
                                  hipFuncAttributeMaxDynamicSharedMemorySize,
                                  131072);
        return 0;
    }();
    (void)_lds_once;

    hipMemsetAsync(stats, 0, 27 * sizeof(double), stream);
    morton_bucket_kernel<<<B_, 1024, 0, stream>>>(x, perm);
    knn_f64_kernel<<<dim3(32, 16), 512, 73728, stream>>>(x, perm, idx, stats);
    bn_prep_kernel<<<1, COUT, 0, stream>>>(stats, w1, b1, gamma, beta, scale_shift);
    mlp_max_kernel<<<(B_ * N_) / 64, 256, 0, stream>>>(x, idx, w1, b1, scale_shift,
                                                       w2, b2, out);
}

// Round 10
// 440.334 us; speedup vs baseline: 1.8492x; 1.0463x over previous
//
#include <hip/hip_runtime.h>
#include <math.h>
#include <float.h>

#define B_   16
#define N_   4096
#define CIN  3
#define COUT 64
#define KNN  20
#define EPS_ 1e-5

// ---------------------------------------------------------------------------
// Workspace layout (5.5MB proven-safe footprint):
//   [0,   216): double stats[27]    (Sum e[6], Sum e e^T upper-tri[21])
//   [256, 768): float scale[64], shift[64]
//   [1024, 1024 + B*N*KNN*4): int idx[B*N*KNN]           (5242880 B)
//   [5243904, +B*N*4): int perm[B*N]  (Morton row order)  (262144 B)
//
// r10 changes (both strictly-local micro-opts inside verified structures):
//   knn: trigger on raw f32 d <= d19f (d19f = exact decoded d-part of
//        bk[19], the r4-verified decode; refreshed only in triggered bodies
//        -> stale-over-enter semantics identical to r1/r9; insert re-checks
//        the full f64 key). sortable() and j16 loads move INSIDE the ~55%
//        triggered body. Prefill slots masked with +INF (its key exceeds
//        any real key -> can never insert). Selection provably identical.
//   mlp: truncation hi/lo split (h >= 0 post-ReLU): hi = bits>>16 (exact
//        remainder via Sterbenz), lo = trunc-bf16(rem). 4 VALU ops/value
//        vs 12 for double-RTNE; error stays ~2^-16*|h|. W2 split stays RTNE.
// ---------------------------------------------------------------------------

__device__ __forceinline__ unsigned expand10(unsigned v) {
    v = (v | (v << 16)) & 0x030000FFu;
    v = (v | (v << 8))  & 0x0300F00Fu;
    v = (v | (v << 4))  & 0x030C30C3u;
    v = (v | (v << 2))  & 0x09249249u;
    return v;
}
__device__ __forceinline__ unsigned quant10(float v) {
    int q = (int)((v + 4.0f) * 128.0f);
    return (unsigned)min(1023, max(0, q));
}

// ===========================================================================
// Kernel 0: per-batch Morton COUNTING sort (verbatim, verified)
// ===========================================================================
__global__ __launch_bounds__(1024) void morton_bucket_kernel(
    const float* __restrict__ x, int* __restrict__ perm)
{
    __shared__ int hist[1024];
    __shared__ int scanbuf[1024];
    __shared__ int offs[1024];
    const int b = blockIdx.x, tid = threadIdx.x;
    const float* xb = x + (size_t)b * N_ * CIN;

    hist[tid] = 0;
    __syncthreads();

    int keys[4];
#pragma unroll
    for (int i = 0; i < 4; ++i) {
        int p = tid + i * 1024;
        float v0 = xb[p * 3 + 0], v1 = xb[p * 3 + 1], v2 = xb[p * 3 + 2];
        unsigned m = (expand10(quant10(v0)) << 2) |
                     (expand10(quant10(v1)) << 1) |
                      expand10(quant10(v2));
        keys[i] = (int)(m >> 20);          // top 10 bits
        atomicAdd(&hist[keys[i]], 1);
    }
    __syncthreads();

    int v = hist[tid];
    scanbuf[tid] = v;
    __syncthreads();
    for (int off = 1; off < 1024; off <<= 1) {   // Hillis-Steele inclusive
        int t = (tid >= off) ? scanbuf[tid - off] : 0;
        __syncthreads();
        scanbuf[tid] += t;
        __syncthreads();
    }
    offs[tid] = scanbuf[tid] - v;                // exclusive base
    __syncthreads();

#pragma unroll
    for (int i = 0; i < 4; ++i) {
        int p = tid + i * 1024;
        int pos = atomicAdd(&offs[keys[i]], 1);
        perm[b * N_ + pos] = p;
    }
}

// ===========================================================================
// Kernel 1: exact-match KNN — r1-verbatim structure with r9 staging
// (pts.w = sqj, j16 side array) and r10 deferred-body micro-opts.
// Order, trigger over-enter semantics, insert, merge, extraction, BN stats
// all unchanged.
// ===========================================================================
__global__ __launch_bounds__(512) void knn_f64_kernel(
    const float* __restrict__ x, const int* __restrict__ perm,
    int* __restrict__ idx_out, double* __restrict__ stats)
{
    extern __shared__ __align__(16) char smem[];
    float4* pts = (float4*)smem;                            // {x,y,z,sqj}
    unsigned short* j16 = (unsigned short*)(smem + 65536);  // [4096] orig idx
    double* scr = (double*)smem;                            // merge view

    const int b    = blockIdx.y;
    const int tid  = threadIdx.x;
    const int wave = tid >> 6;
    const int lane = tid & 63;
    const int r    = wave >> 2;     // row-group 0..1
    const int q    = wave & 3;      // interleave class: positions p&3==q
    const float* xb = x + (size_t)b * N_ * CIN;

    for (int p = tid; p < N_; p += 512) {
        int j = perm[b * N_ + p];                // coalesced
        float v0 = xb[j * 3 + 0], v1 = xb[j * 3 + 1], v2 = xb[j * 3 + 2];
        float sq = __fadd_rn(__fadd_rn(__fmul_rn(v0, v0),
                                       __fmul_rn(v1, v1)),
                             __fmul_rn(v2, v2));
        pts[p] = make_float4(v0, v1, v2, sq);
        j16[p] = (unsigned short)j;
    }
    __syncthreads();

    const int rowg = blockIdx.x * 128 + r * 64;  // wave's first row pos
    const float4 xf = pts[rowg + lane];
    const int jrow  = j16[rowg + lane];
    const float sqi = xf.w;                      // staged, bit-identical

    auto mkd = [&](float4 p) -> float {
        float dot = __fadd_rn(__fadd_rn(__fmul_rn(xf.x, p.x),
                                        __fmul_rn(xf.y, p.y)),
                              __fmul_rn(xf.z, p.z));
        return __fsub_rn(__fadd_rn(sqi, p.w), __fmul_rn(2.0f, dot));
    };
    auto sortable = [&](float d) -> unsigned {
        unsigned u = __float_as_uint(d);
        return u ^ (0x80000000u | (unsigned)((int)u >> 31));
    };

    double bk[KNN];
#pragma unroll
    for (int k = 0; k < KNN; ++k) bk[k] = 1e300;     // sentinels (sorted)

    auto insert = [&](double key) {                  // VERBATIM verified
        if (key < bk[KNN - 1]) {
            double m = key;                  // carries max(bk_old[i-1], key)
#pragma unroll
            for (int k = 0; k < KNN; ++k) {
                double old = bk[k];
                bk[k] = fmin(m, old);
                m     = fmax(old, m);
            }
        }
    };

    const int ta = rowg >> 2;            // wave-uniform anchor (SGPR math)
#pragma unroll
    for (int k = 0; k < KNN; ++k) {
        int p = 4 * ((ta + k) & 1023) + q;
        float4 a = pts[p];
        insert(fma((double)sortable(mkd(a)), 4096.0,
                   (double)(unsigned)j16[p]));
    }

    // d19f = exact d of the current 20th-best key (r4-verified decode);
    // refreshed only where bk can change (triggered bodies) -> stale
    // between bodies = over-enter only (insert re-checks the full key).
    float d19f;
    {
        unsigned s19 = (unsigned)trunc(bk[KNN - 1] * (1.0 / 4096.0));
        unsigned u = (s19 >= 0x80000000u) ? (s19 ^ 0x80000000u) : ~s19;
        d19f = __uint_as_float(u);
    }

    for (int s = 0; s < 1024; s += 4) {
        int v0 = ((s + 0) * 509) & 1023;
        int v1 = ((s + 1) * 509) & 1023;
        int v2 = ((s + 2) * 509) & 1023;
        int v3 = ((s + 3) * 509) & 1023;
        int p0 = 4 * ((ta + v0) & 1023) + q;
        int p1 = 4 * ((ta + v1) & 1023) + q;
        int p2 = 4 * ((ta + v2) & 1023) + q;
        int p3 = 4 * ((ta + v3) & 1023) + q;
        float4 a0 = pts[p0];
        float4 a1 = pts[p1];
        float4 a2 = pts[p2];
        float4 a3 = pts[p3];
        float d0 = mkd(a0), d1 = mkd(a1), d2 = mkd(a2), d3 = mkd(a3);
        // prefill positions masked with +INF: sortable(+INF)=0xFF800000,
        // key = 0xFF800000*4096 + j exceeds any real key -> never inserts.
        d0 = (v0 < 20) ? INFINITY : d0;
        d1 = (v1 < 20) ? INFINITY : d1;
        d2 = (v2 < 20) ? INFINITY : d2;
        d3 = (v3 < 20) ? INFINITY : d3;
        if ((d0 <= d19f) | (d1 <= d19f) | (d2 <= d19f) | (d3 <= d19f)) {
            unsigned j0 = j16[p0], j1 = j16[p1], j2 = j16[p2], j3 = j16[p3];
            insert(fma((double)sortable(d0), 4096.0, (double)j0));
            insert(fma((double)sortable(d1), 4096.0, (double)j1));
            insert(fma((double)sortable(d2), 4096.0, (double)j2));
            insert(fma((double)sortable(d3), 4096.0, (double)j3));
            unsigned s19 = (unsigned)trunc(bk[KNN - 1] * (1.0 / 4096.0));
            unsigned u = (s19 >= 0x80000000u) ? (s19 ^ 0x80000000u) : ~s19;
            d19f = __uint_as_float(u);
        }
    }
    __syncthreads();    // scans done; pts dead (xf in regs) -> scr valid

    if (q & 1) {
        int base = ((r * 2 + (q >> 1)) * 64 + lane) * KNN;
#pragma unroll
        for (int k = 0; k < KNN; ++k) scr[base + k] = bk[k];
    }
    __syncthreads();
    if (!(q & 1)) {                 // q0 absorbs q1; q2 absorbs q3
        int base = ((r * 2 + (q >> 1)) * 64 + lane) * KNN;
#pragma unroll
        for (int k = 0; k < KNN; ++k) insert(scr[base + k]);
    }
    __syncthreads();
    if (q == 2) {
        int base = ((r * 2 + 1) * 64 + lane) * KNN;
#pragma unroll
        for (int k = 0; k < KNN; ++k) scr[base + k] = bk[k];
    }
    __syncthreads();
    if (q == 0) {
        int base = ((r * 2 + 1) * 64 + lane) * KNN;
#pragma unroll
        for (int k = 0; k < KNN; ++k) insert(scr[base + k]);

        const long long row = (long long)b * N_ + jrow;
        int bi[KNN];
#pragma unroll
        for (int k = 0; k < KNN; ++k) {
            double sp = trunc(bk[k] * (1.0 / 4096.0));
            bi[k] = (int)(bk[k] - sp * 4096.0);
        }
#pragma unroll
        for (int k = 0; k < KNN; ++k) idx_out[row * KNN + k] = bi[k];

        float acc[27];
#pragma unroll
        for (int t = 0; t < 27; ++t) acc[t] = 0.0f;
#pragma unroll
        for (int k = 0; k < KNN; ++k) {
            const float* pj = xb + bi[k] * 3;
            float e[6] = { xf.x, xf.y, xf.z,
                           pj[0] - xf.x, pj[1] - xf.y, pj[2] - xf.z };
            int t = 6;
#pragma unroll
            for (int a = 0; a < 6; ++a) {
                acc[a] += e[a];
#pragma unroll
                for (int bb = a; bb < 6; ++bb) acc[t++] += e[a] * e[bb];
            }
        }
#pragma unroll
        for (int t = 0; t < 27; ++t) {
            float v = acc[t];
            v += __shfl_down(v, 32); v += __shfl_down(v, 16);
            v += __shfl_down(v, 8);  v += __shfl_down(v, 4);
            v += __shfl_down(v, 2);  v += __shfl_down(v, 1);
            acc[t] = v;
        }
        if (lane == 0) {
#pragma unroll
            for (int t = 0; t < 27; ++t) atomicAdd(&stats[t], (double)acc[t]);
        }
    }
}

// ===========================================================================
// Kernel 2: fold stats -> per-channel scale/shift (unchanged, verified)
// ===========================================================================
__global__ void bn_prep_kernel(
    const double* __restrict__ stats,
    const float* __restrict__ w1, const float* __restrict__ b1,
    const float* __restrict__ gamma, const float* __restrict__ beta,
    float* __restrict__ scale_shift)
{
    const int c = threadIdx.x;
    double s[6], S[6][6];
#pragma unroll
    for (int a = 0; a < 6; ++a) s[a] = stats[a];
    int t = 6;
#pragma unroll
    for (int a = 0; a < 6; ++a)
#pragma unroll
        for (int bb = a; bb < 6; ++bb) { S[a][bb] = stats[t]; S[bb][a] = stats[t]; ++t; }

    const double M = (double)B_ * N_ * KNN;
    double wc[6];
#pragma unroll
    for (int j = 0; j < 6; ++j) wc[j] = (double)w1[j * COUT + c];
    const double b1c = (double)b1[c];

    double sw = 0.0;
#pragma unroll
    for (int j = 0; j < 6; ++j) sw += s[j] * wc[j];
    double mean = sw / M + b1c;

    double qq = 0.0;
#pragma unroll
    for (int a = 0; a < 6; ++a)
#pragma unroll
        for (int bb = 0; bb < 6; ++bb) qq += S[a][bb] * wc[a] * wc[bb];
    double ex2 = (qq + 2.0 * b1c * sw) / M + b1c * b1c;
    double var = ex2 - mean * mean;

    double sc = (double)gamma[c] / sqrt(var + (double)EPS_);
    double sh = (double)beta[c] - mean * sc;
    scale_shift[c]        = (float)sc;
    scale_shift[COUT + c] = (float)sh;
}

// ===========================================================================
// Kernel 3: fused edge->lin1->BN->ReLU->lin2->max via split-bf16 MFMA.
// r8 pipeline (verified) + r10 truncation hi/lo split in the k-loop.
// ===========================================================================
typedef __attribute__((ext_vector_type(8))) short short8;
typedef __attribute__((ext_vector_type(4))) float f32x4;

__device__ __forceinline__ unsigned short f2bf_rn(float f) {
    unsigned u = __float_as_uint(f);
    unsigned lsb = (u >> 16) & 1u;
    return (unsigned short)((u + 0x7FFFu + lsb) >> 16);
}
__device__ __forceinline__ float bf2f(unsigned short h) {
    return __uint_as_float(((unsigned)h) << 16);
}

__global__ __launch_bounds__(256) void mlp_max_kernel(
    const float* __restrict__ x, const int* __restrict__ idx,
    const float* __restrict__ w1, const float* __restrict__ b1,
    const float* __restrict__ scale_shift,
    const float* __restrict__ w2, const float* __restrict__ b2,
    float* __restrict__ out)
{
    __shared__ __align__(16) unsigned short hbuf[4][2][16][136];  // 34.8KB
    __shared__ int idxs[4][320];                                  // +5KB

    const int tid  = threadIdx.x;
    const int wv   = tid >> 6;
    const int lane = tid & 63;
    const int g    = lane >> 4;      // 16-lane group (k-chunk select)
    const int r15  = lane & 15;      // row (A) / col (B,C) within tile

    const int R     = (blockIdx.x * 4 + wv) * 16;   // wave's first row
    const int bbase = (R >> 12) << 12;              // batch slab start row

    // ---- stage this wave's idx block into LDS (coalesced, wave-private) --
    {
        const int* ip = idx + (size_t)R * KNN;
#pragma unroll
        for (int i = 0; i < 5; ++i)
            idxs[wv][lane + i * 64] = ip[lane + i * 64];
    }

    const int c  = lane;
    const float sc = scale_shift[c];
    const float sh = scale_shift[COUT + c];
    float w1p[6];
#pragma unroll
    for (int j = 0; j < 6; ++j) w1p[j] = w1[j * COUT + c] * sc;
    const float b1p = fmaf(b1[c], sc, sh);
    const float dw0 = w1p[0] - w1p[3];
    const float dw1 = w1p[1] - w1p[4];
    const float dw2 = w1p[2] - w1p[5];

    short8 Wh[2][4], Wl[2][4];
#pragma unroll
    for (int t = 0; t < 2; ++t)
#pragma unroll
        for (int n = 0; n < 4; ++n) {
            short8 hv, lv;
#pragma unroll
            for (int jj = 0; jj < 8; ++jj) {
                float w = w2[(t * 32 + g * 8 + jj) * COUT + n * 16 + r15];
                unsigned short hi = f2bf_rn(w);
                unsigned short lo = f2bf_rn(w - bf2f(hi));
                hv[jj] = (short)hi;
                lv[jj] = (short)lo;
            }
            Wh[t][n] = hv;
            Wl[t][n] = lv;
        }

    float base[16];
#pragma unroll
    for (int r = 0; r < 16; ++r) {
        const float* pi = x + (size_t)(R + r) * 3;
        float v = b1p;
        v = fmaf(pi[0], dw0, v);
        v = fmaf(pi[1], dw1, v);
        v = fmaf(pi[2], dw2, v);
        base[r] = v;
    }

    // ---- prefetch k=0 neighbor coords ----
    float px[16], py[16], pz[16];
#pragma unroll
    for (int r = 0; r < 16; ++r) {
        int j = idxs[wv][r * KNN];                    // wave-uniform (LDS)
        const float* pj = x + (size_t)(bbase + j) * 3;
        px[r] = pj[0]; py[r] = pj[1]; pz[r] = pj[2];
    }

    f32x4 mx[4];
#pragma unroll
    for (int n = 0; n < 4; ++n) {
        mx[n][0] = -INFINITY; mx[n][1] = -INFINITY;
        mx[n][2] = -INFINITY; mx[n][3] = -INFINITY;
    }

    for (int k = 0; k < KNN; ++k) {
        unsigned short* hb = &hbuf[wv][k & 1][0][0];

        // Truncation split (h >= 0 post-ReLU): hi = bits>>16; rem exact.
#pragma unroll
        for (int r = 0; r < 16; ++r) {
            float h = base[r];
            h = fmaf(px[r], w1p[3], h);
            h = fmaf(py[r], w1p[4], h);
            h = fmaf(pz[r], w1p[5], h);
            h = fmaxf(h, 0.0f);
            unsigned hu = __float_as_uint(h);
            unsigned short hi = (unsigned short)(hu >> 16);
            float rem = h - __uint_as_float(hu & 0xFFFF0000u);
            unsigned short lo = (unsigned short)(__float_as_uint(rem) >> 16);
            hb[r * 136 + c]      = hi;
            hb[r * 136 + 64 + c] = lo;
        }

        // prefetch k+1: 48 independent loads issued BEFORE the MFMA block
        if (k + 1 < KNN) {
#pragma unroll
            for (int r = 0; r < 16; ++r) {
                int j = idxs[wv][r * KNN + k + 1];     // LDS, wave-uniform
                const float* pj = x + (size_t)(bbase + j) * 3;
                px[r] = pj[0]; py[r] = pj[1]; pz[r] = pj[2];
            }
        }

        const unsigned short* rpnt = hb + r15 * 136;
        short8 Ah0 = *(const short8*)(rpnt + g * 8);
        short8 Ah1 = *(const short8*)(rpnt + 32 + g * 8);
        short8 Al0 = *(const short8*)(rpnt + 64 + g * 8);
        short8 Al1 = *(const short8*)(rpnt + 96 + g * 8);

#pragma unroll
        for (int n = 0; n < 4; ++n) {
            f32x4 a = {0.0f, 0.0f, 0.0f, 0.0f};
            a = __builtin_amdgcn_mfma_f32_16x16x32_bf16(Ah0, Wh[0][n], a, 0, 0, 0);
            a = __builtin_amdgcn_mfma_f32_16x16x32_bf16(Ah1, Wh[1][n], a, 0, 0, 0);
            a = __builtin_amdgcn_mfma_f32_16x16x32_bf16(Al0, Wh[0][n], a, 0, 0, 0);
            a = __builtin_amdgcn_mfma_f32_16x16x32_bf16(Al1, Wh[1][n], a, 0, 0, 0);
            a = __builtin_amdgcn_mfma_f32_16x16x32_bf16(Ah0, Wl[0][n], a, 0, 0, 0);
            a = __builtin_amdgcn_mfma_f32_16x16x32_bf16(Ah1, Wl[1][n], a, 0, 0, 0);
            mx[n][0] = fmaxf(mx[n][0], a[0]);
            mx[n][1] = fmaxf(mx[n][1], a[1]);
            mx[n][2] = fmaxf(mx[n][2], a[2]);
            mx[n][3] = fmaxf(mx[n][3], a[3]);
        }
    }

    float b2v[4];
#pragma unroll
    for (int n = 0; n < 4; ++n) b2v[n] = b2[n * 16 + r15];
#pragma unroll
    for (int n = 0; n < 4; ++n)
#pragma unroll
        for (int rr = 0; rr < 4; ++rr)
            out[(size_t)(R + g * 4 + rr) * COUT + n * 16 + r15] =
                mx[n][rr] + b2v[n];
}

// ===========================================================================
extern "C" void kernel_launch(void* const* d_in, const int* in_sizes, int n_in,
                              void* d_out, int out_size, void* d_ws, size_t ws_size,
                              hipStream_t stream)
{
    const float* x     = (const float*)d_in[0];
    const float* w1    = (const float*)d_in[2];
    const float* b1    = (const float*)d_in[3];
    const float* gamma = (const float*)d_in[4];
    const float* beta  = (const float*)d_in[5];
    const float* w2    = (const float*)d_in[6];
    const float* b2    = (const float*)d_in[7];
    float* out = (float*)d_out;

    char*   ws          = (char*)d_ws;
    double* stats       = (double*)ws;
    float*  scale_shift = (float*)(ws + 256);
    int*    idx         = (int*)(ws + 1024);
    int*    perm        = (int*)(ws + 1024 + (size_t)B_ * N_ * KNN * 4);

    // one-time opt-in for >64KB dynamic LDS; host-side, graph-capture-safe.
    static int _lds_once = []() {
        (void)hipFuncSetAttribute((const void*)knn_f64_kernel,
                                  hipFuncAttributeMaxDynamicSharedMemorySize,
                                  131072);
        return 0;
    }();
    (void)_lds_once;

    hipMemsetAsync(stats, 0, 27 * sizeof(double), stream);
    morton_bucket_kernel<<<B_, 1024, 0, stream>>>(x, perm);
    knn_f64_kernel<<<dim3(32, 16), 512, 73728, stream>>>(x, perm, idx, stats);
    bn_prep_kernel<<<1, COUT, 0, stream>>>(stats, w1, b1, gamma, beta, scale_shift);
    mlp_max_kernel<<<(B_ * N_) / 64, 256, 0, stream>>>(x, idx, w1, b1, scale_shift,
                                                       w2, b2, out);
}